// Round 13
// baseline (496.301 us; speedup 1.0000x reference)
//
#include <hip/hip_runtime.h>
#include <hip/hip_fp16.h>
#include <math.h>

#define NN 40000
#define NE 640000
#define NG 64
#define DINV 64
#define HDV 128
#define DEV 16
#define EF (NE + NN)
#define PSPLIT 16
#define NSB ((NN + 255) / 256)   // 157 scan blocks
#define BK 16

typedef float v2f __attribute__((ext_vector_type(2)));

// position p <-> channel: lane L (half-wave h=L>>5) owns positions 4*(L&31)+2*h+{0,1}
// = channels h*64 + 2*(L&31) + {0,1}.  chan(p) = 2*(p>>2) + (p&1) + 64*((p>>1)&1)
__device__ __forceinline__ int chan_of_pos(int p) { return ((p >> 2) << 1) + (p & 1) + (((p >> 1) & 1) << 6); }

// ---------------- DPP half-wave sums: lane31 = sum(l 0..31), lane63 = sum(32..63) ----------------
template <int CTRL>
__device__ __forceinline__ float dpp_mov_f(float x) {
    return __builtin_bit_cast(float,
        __builtin_amdgcn_update_dpp(0, __builtin_bit_cast(int, x), CTRL, 0xf, 0xf, true));
}
__device__ __forceinline__ v2f half_sums(float x) {
    x += dpp_mov_f<0x111>(x);   // row_shr:1
    x += dpp_mov_f<0x112>(x);   // row_shr:2
    x += dpp_mov_f<0x114>(x);   // row_shr:4
    x += dpp_mov_f<0x118>(x);   // row_shr:8
    x += dpp_mov_f<0x142>(x);   // row_bcast:15 -> lane31/lane63 hold half sums
    float s0 = __builtin_bit_cast(float, __builtin_amdgcn_readlane(__builtin_bit_cast(int, x), 31));
    float s1 = __builtin_bit_cast(float, __builtin_amdgcn_readlane(__builtin_bit_cast(int, x), 63));
    return v2f{s0, s1};
}

// ---------------- CSR construction ----------------

__global__ void k_count(const int* __restrict__ dst, int* __restrict__ cnt) {
    int e = blockIdx.x * 256 + threadIdx.x;
    if (e < NE) atomicAdd(&cnt[dst[e]], 1);
}

// hierarchical coalesced scan of (cnt[i]+1): a) block sums, b) scan sums, c) final
__global__ __launch_bounds__(256) void k_scan_a(const int* __restrict__ cnt, int* __restrict__ bsum) {
    int i = blockIdx.x * 256 + threadIdx.x;
    int v = (i < NN) ? cnt[i] + 1 : 0;
    __shared__ int s[256];
    s[threadIdx.x] = v;
    __syncthreads();
    for (int off = 128; off > 0; off >>= 1) {
        if (threadIdx.x < off) s[threadIdx.x] += s[threadIdx.x + off];
        __syncthreads();
    }
    if (threadIdx.x == 0) bsum[blockIdx.x] = s[0];
}

__global__ __launch_bounds__(256) void k_scan_b(const int* __restrict__ bsum, int* __restrict__ boff) {
    int t = threadIdx.x;
    int v = (t < NSB) ? bsum[t] : 0;
    __shared__ int s[256];
    s[t] = v;
    __syncthreads();
    for (int off = 1; off < 256; off <<= 1) {
        int add = (t >= off) ? s[t - off] : 0;
        __syncthreads();
        s[t] += add;
        __syncthreads();
    }
    boff[t] = s[t] - v;   // exclusive
}

__global__ __launch_bounds__(256) void k_scan_c(const int* __restrict__ cnt, const int* __restrict__ boff,
                                                int* __restrict__ rowptr, int* __restrict__ cursor) {
    int i = blockIdx.x * 256 + threadIdx.x;
    int t = threadIdx.x;
    int v = (i < NN) ? cnt[i] + 1 : 0;
    __shared__ int s[256];
    s[t] = v;
    __syncthreads();
    for (int off = 1; off < 256; off <<= 1) {
        int add = (t >= off) ? s[t - off] : 0;
        __syncthreads();
        s[t] += add;
        __syncthreads();
    }
    int excl = boff[blockIdx.x] + s[t] - v;
    if (i < NN) {
        rowptr[i] = excl;
        cursor[i] = excl;
        if (i == NN - 1) rowptr[NN] = excl + v;   // = EF
    }
}

// fill CSR adjacency AND edge attrs in CSR order (linear s_load stream for k_gat)
__global__ void k_fill(const int* __restrict__ src, const int* __restrict__ dst,
                       const float* __restrict__ edge_attr,
                       int* __restrict__ cursor, int* __restrict__ csr_src, float* __restrict__ csr_ea) {
    int e = blockIdx.x * 256 + threadIdx.x;
    if (e < NE) {
        int d = dst[e];
        int p = atomicAdd(&cursor[d], 1);
        csr_src[p] = src[e];
        const float4* s4 = (const float4*)&edge_attr[(size_t)e * DEV];
        float4* d4 = (float4*)&csr_ea[(size_t)p * DEV];
        d4[0] = s4[0]; d4[1] = s4[1]; d4[2] = s4[2]; d4[3] = s4[3];
    }
}

// ---------------- weight permutation (all 3 layers) + graph bounds, one launch ----------------
__global__ void k_wperm_all(const float* __restrict__ w1l, const float* __restrict__ w1r,
                            const float* __restrict__ w2l, const float* __restrict__ w2r,
                            const float* __restrict__ w3l, const float* __restrict__ w3r,
                            float* __restrict__ wlp, float* __restrict__ wrp,
                            const int* __restrict__ batch, int* __restrict__ gstart) {
    int t = threadIdx.x;
    if (blockIdx.x == gridDim.x - 1) {   // graph boundaries via binary search (batch sorted)
        int g = t;
        if (g > NG) return;
        int lo = 0, hi = NN;
        while (lo < hi) {
            int mid = (lo + hi) >> 1;
            if (batch[mid] < g) lo = mid + 1; else hi = mid;
        }
        gstart[g] = lo;
        return;
    }
    int i = blockIdx.x * 256 + t;
    if (i >= 3 * HDV * HDV) return;
    int layer = i / (HDV * HDV);
    int r = i - layer * HDV * HDV;
    int p = r & 127, kp = r >> 7;
    int K = (layer == 0) ? DINV : HDV;
    if (kp >= K) return;
    int kr = (layer == 0) ? kp : chan_of_pos(kp);   // rows positional for layers 2,3
    int cc = chan_of_pos(p);
    const float* wl = (layer == 0) ? w1l : (layer == 1) ? w2l : w3l;
    const float* wr = (layer == 0) ? w1r : (layer == 1) ? w2r : w3r;
    wlp[i] = wl[kr * HDV + cc];
    wrp[i] = wr[kr * HDV + cc];
}

// ---------------- dense transforms: XL = A@Wl (fp16 out), XR = A@Wr (fp32 out) ----------------
// 128x128 tile, 8x8 per-thread register blocking, double-buffered LDS, BK=16, 1 sync/K-step.
__global__ __launch_bounds__(256) void k_gemm(const float* __restrict__ A, int K,
                                              const float* __restrict__ Wl, const float* __restrict__ Wr,
                                              __half* __restrict__ XLh, float* __restrict__ XR,
                                              const double* __restrict__ bnsum, const double* __restrict__ bnsumsq,
                                              const float* __restrict__ g, const float* __restrict__ bb) {
    __shared__ float As[2][BK][128];
    __shared__ float Bs[2][BK][128];
    __shared__ float ssc[HDV], ssh[HDV];
    int t = threadIdx.x;
    if (bnsum && t < HDV) {   // BN scale/shift of previous layer (positional index t)
        int c = chan_of_pos(t);
        double mu = bnsum[t] * (1.0 / NN);
        double var = bnsumsq[t] * (1.0 / NN) - mu * mu;
        double inv = rsqrt(var + 1e-5);
        float sc = (float)(inv * (double)g[c]);
        ssc[t] = sc;
        ssh[t] = bb[c] - (float)mu * sc;
    }
    __syncthreads();
    int rb = blockIdx.x * 128;
    const float* __restrict__ Bg = blockIdx.y ? Wr : Wl;
    int tx = t & 15, ty = t >> 4;
    int lr_ = t >> 1, lk = (t & 1) * 8;     // A: two float4 (row=lr_, k=lk.. and lk+4..)
    int bkr = t >> 4, bc = (t & 15) * 8;    // B: two float4 (k=bkr, col=bc.. and bc+4..)

    auto bnfix = [&](float4& v, int c0) {
        v.x = fmaf(v.x, ssc[c0 + 0], ssh[c0 + 0]); v.x = fmaxf(v.x, 0.01f * v.x);
        v.y = fmaf(v.y, ssc[c0 + 1], ssh[c0 + 1]); v.y = fmaxf(v.y, 0.01f * v.y);
        v.z = fmaf(v.z, ssc[c0 + 2], ssh[c0 + 2]); v.z = fmaxf(v.z, 0.01f * v.z);
        v.w = fmaf(v.w, ssc[c0 + 3], ssh[c0 + 3]); v.w = fmaxf(v.w, 0.01f * v.w);
    };
    auto loadA = [&](int k0, float4& a0, float4& a1) {
        if (rb + lr_ < NN) {
            a0 = *(const float4*)&A[(size_t)(rb + lr_) * K + k0 + lk];
            a1 = *(const float4*)&A[(size_t)(rb + lr_) * K + k0 + lk + 4];
        } else {
            a0 = float4{0.f, 0.f, 0.f, 0.f};
            a1 = float4{0.f, 0.f, 0.f, 0.f};
        }
        if (bnsum) { bnfix(a0, k0 + lk); bnfix(a1, k0 + lk + 4); }
    };

    // prologue: stage tile 0
    float4 a0, a1, b0, b1;
    loadA(0, a0, a1);
    b0 = *(const float4*)&Bg[(size_t)bkr * HDV + bc];
    b1 = *(const float4*)&Bg[(size_t)bkr * HDV + bc + 4];
    #pragma unroll
    for (int j = 0; j < 4; ++j) {
        As[0][lk + j][lr_] = ((const float*)&a0)[j];
        As[0][lk + 4 + j][lr_] = ((const float*)&a1)[j];
    }
    *(float4*)&Bs[0][bkr][bc] = b0;
    *(float4*)&Bs[0][bkr][bc + 4] = b1;
    __syncthreads();

    float acc[8][8] = {};
    int cur = 0;
    for (int k0 = 0; k0 < K; k0 += BK) {
        bool more = (k0 + BK) < K;
        if (more) {   // issue next tile's loads; latency hides under compute below
            loadA(k0 + BK, a0, a1);
            b0 = *(const float4*)&Bg[(size_t)(k0 + BK + bkr) * HDV + bc];
            b1 = *(const float4*)&Bg[(size_t)(k0 + BK + bkr) * HDV + bc + 4];
        }
        #pragma unroll
        for (int kk = 0; kk < BK; ++kk) {
            float a8[8], b8[8];
            *(float4*)&a8[0] = *(const float4*)&As[cur][kk][ty * 8];
            *(float4*)&a8[4] = *(const float4*)&As[cur][kk][ty * 8 + 4];
            *(float4*)&b8[0] = *(const float4*)&Bs[cur][kk][tx * 8];
            *(float4*)&b8[4] = *(const float4*)&Bs[cur][kk][tx * 8 + 4];
            #pragma unroll
            for (int ii = 0; ii < 8; ++ii)
                #pragma unroll
                for (int jj = 0; jj < 8; ++jj)
                    acc[ii][jj] = fmaf(a8[ii], b8[jj], acc[ii][jj]);
        }
        if (more) {
            int nxt = cur ^ 1;
            #pragma unroll
            for (int j = 0; j < 4; ++j) {
                As[nxt][lk + j][lr_] = ((const float*)&a0)[j];
                As[nxt][lk + 4 + j][lr_] = ((const float*)&a1)[j];
            }
            *(float4*)&Bs[nxt][bkr][bc] = b0;
            *(float4*)&Bs[nxt][bkr][bc + 4] = b1;
            __syncthreads();
            cur = nxt;
        }
    }
    if (blockIdx.y == 0) {   // XL: fp16 output
        #pragma unroll
        for (int ii = 0; ii < 8; ++ii) {
            int row = rb + ty * 8 + ii;
            if (row < NN) {
                __half2 h4[4];
                #pragma unroll
                for (int jj = 0; jj < 4; ++jj)
                    h4[jj] = __half2{__float2half_rn(acc[ii][2 * jj]), __float2half_rn(acc[ii][2 * jj + 1])};
                *(__half2*)&XLh[(size_t)row * HDV + tx * 8 + 0] = h4[0];
                *(__half2*)&XLh[(size_t)row * HDV + tx * 8 + 2] = h4[1];
                *(__half2*)&XLh[(size_t)row * HDV + tx * 8 + 4] = h4[2];
                *(__half2*)&XLh[(size_t)row * HDV + tx * 8 + 6] = h4[3];
            }
        }
    } else {                 // XR: fp32 output
        #pragma unroll
        for (int ii = 0; ii < 8; ++ii) {
            int row = rb + ty * 8 + ii;
            if (row < NN) {
                float4 v0 = {acc[ii][0], acc[ii][1], acc[ii][2], acc[ii][3]};
                float4 v1 = {acc[ii][4], acc[ii][5], acc[ii][6], acc[ii][7]};
                *(float4*)&XR[(size_t)row * HDV + tx * 8] = v0;
                *(float4*)&XR[(size_t)row * HDV + tx * 8 + 4] = v1;
            }
        }
    }
}

// ---------------- GATv2 per-node softmax aggregation ----------------
// one wave per node; half-wave h owns head h: lane L holds channels h*64+2*(L&31)+{0,1}.
// Pairwise edge processing: both XL gathers + both attr streams issued before compute,
// two independent DPP chains interleaved.
__global__ __launch_bounds__(256) void k_gat(const __half* __restrict__ XLh, const float* __restrict__ XR,
                                             const int* __restrict__ rowptr, const int* __restrict__ csr_src,
                                             const float* __restrict__ csr_ea,
                                             const float* __restrict__ we, const float* __restrict__ att,
                                             const float* __restrict__ cb, float* __restrict__ hpre) {
    int t = threadIdx.x;
    int L = t & 63;
    int l5 = L & 31, hh = L >> 5;
    int c0 = hh * 64 + 2 * l5;          // channel pair (c0, c0+1), same head
    int poff = 4 * l5 + 2 * hh;         // position pair (poff, poff+1)
    int d = __builtin_amdgcn_readfirstlane(blockIdx.x * 4 + (t >> 6));
    v2f rwe0[DEV / 2], rwe1[DEV / 2];   // k-pairs per slot: 32 VGPRs
    #pragma unroll
    for (int j = 0; j < DEV / 2; ++j) {
        rwe0[j] = v2f{we[(2 * j) * HDV + c0],     we[(2 * j + 1) * HDV + c0]};
        rwe1[j] = v2f{we[(2 * j) * HDV + c0 + 1], we[(2 * j + 1) * HDV + c0 + 1]};
    }
    const float LOG2E = 1.4426950408889634f;
    v2f attv = {att[c0] * LOG2E, att[c0 + 1] * LOG2E};
    v2f xr = *(const v2f*)&XR[(size_t)d * HDV + poff];
    int istart = rowptr[d];
    int iend = rowptr[d + 1] - 1;       // real edges only; last slot = self-loop
    int deg = iend - istart;
    float Da = 0.f, Db = 0.f;           // own head's denominator
    v2f Aa = {0.f, 0.f}, Ab = {0.f, 0.f};
    v2f eesum = {0.f, 0.f};
    unsigned xoff = ((unsigned)poff << 1);   // fp16 byte offset within row

    auto body1 = [&](int i) {
        int sx = csr_src[i];
        const v2f* eap = (const v2f*)(csr_ea + (size_t)i * DEV);
        __half2 xlh = *(const __half2*)((const char*)XLh + (((unsigned)sx << 8) + xoff));
        v2f xl = {__half2float(xlh.x), __half2float(xlh.y)};
        v2f e0 = {0.f, 0.f}, e1 = {0.f, 0.f};
        #pragma unroll
        for (int j = 0; j < DEV / 2; ++j) {
            v2f ea2 = eap[j];
            e0 = __builtin_elementwise_fma(ea2, rwe0[j], e0);
            e1 = __builtin_elementwise_fma(ea2, rwe1[j], e1);
        }
        v2f eev = {e0.x + e0.y, e1.x + e1.y};
        eesum += eev;
        v2f m = xl + xr + eev;
        v2f lr = __builtin_elementwise_max(m, m * 0.2f);
        float cl = fmaf(lr.y, attv.y, lr.x * attv.x);
        v2f s = half_sums(cl);
        float es = __builtin_amdgcn_exp2f(hh ? s.y : s.x);
        Da += es;
        Aa = __builtin_elementwise_fma(v2f{es, es}, xl, Aa);
    };

    auto body2 = [&](int i) {
        int sx0 = csr_src[i];
        int sx1 = csr_src[i + 1];
        __half2 xlh0 = *(const __half2*)((const char*)XLh + (((unsigned)sx0 << 8) + xoff));
        __half2 xlh1 = *(const __half2*)((const char*)XLh + (((unsigned)sx1 << 8) + xoff));
        const v2f* eap0 = (const v2f*)(csr_ea + (size_t)i * DEV);
        const v2f* eap1 = eap0 + DEV / 2;
        v2f e00 = {0.f, 0.f}, e01 = {0.f, 0.f}, e10 = {0.f, 0.f}, e11 = {0.f, 0.f};
        #pragma unroll
        for (int j = 0; j < DEV / 2; ++j) {
            v2f ea0 = eap0[j], ea1 = eap1[j];
            e00 = __builtin_elementwise_fma(ea0, rwe0[j], e00);
            e01 = __builtin_elementwise_fma(ea0, rwe1[j], e01);
            e10 = __builtin_elementwise_fma(ea1, rwe0[j], e10);
            e11 = __builtin_elementwise_fma(ea1, rwe1[j], e11);
        }
        v2f eev0 = {e00.x + e00.y, e01.x + e01.y};
        v2f eev1 = {e10.x + e10.y, e11.x + e11.y};
        eesum += eev0 + eev1;
        v2f xl0 = {__half2float(xlh0.x), __half2float(xlh0.y)};
        v2f xl1 = {__half2float(xlh1.x), __half2float(xlh1.y)};
        v2f m0 = xl0 + xr + eev0;
        v2f m1 = xl1 + xr + eev1;
        v2f lr0 = __builtin_elementwise_max(m0, m0 * 0.2f);
        v2f lr1 = __builtin_elementwise_max(m1, m1 * 0.2f);
        float cl0 = fmaf(lr0.y, attv.y, lr0.x * attv.x);
        float cl1 = fmaf(lr1.y, attv.y, lr1.x * attv.x);
        v2f s0 = half_sums(cl0);
        v2f s1 = half_sums(cl1);
        float es0 = __builtin_amdgcn_exp2f(hh ? s0.y : s0.x);
        float es1 = __builtin_amdgcn_exp2f(hh ? s1.y : s1.x);
        Da += es0; Db += es1;
        Aa = __builtin_elementwise_fma(v2f{es0, es0}, xl0, Aa);
        Ab = __builtin_elementwise_fma(v2f{es1, es1}, xl1, Ab);
    };

    int i = istart;
    if (deg & 1) { body1(i); ++i; }
    for (; i < iend; i += 2) body2(i);
    {   // self-loop: xl = own row, ee = mean of edge ee's (0 if deg==0)
        __half2 xlh = *(const __half2*)&XLh[(size_t)d * HDV + poff];
        v2f xls = {__half2float(xlh.x), __half2float(xlh.y)};
        v2f eeself = eesum * (1.0f / (float)max(deg, 1));
        v2f m = xls + xr + eeself;
        v2f lr = __builtin_elementwise_max(m, m * 0.2f);
        float cl = fmaf(lr.y, attv.y, lr.x * attv.x);
        v2f s = half_sums(cl);
        float es = __builtin_amdgcn_exp2f(hh ? s.y : s.x);
        Da += es;
        Aa = __builtin_elementwise_fma(v2f{es, es}, xls, Aa);
    }
    float D = Da + Db;
    v2f A = Aa + Ab;
    float dinv = 1.0f / (D + 1e-16f);
    v2f h = A * v2f{dinv, dinv} + v2f{cb[c0], cb[c0 + 1]};
    *(v2f*)&hpre[(size_t)d * HDV + poff] = h;
}

// ---------------- BatchNorm stats (position-indexed, fp32 partials) ----------------

__global__ __launch_bounds__(256) void k_bn_stats(const float* __restrict__ hpre,
                                                  double* __restrict__ bnsum, double* __restrict__ bnsumsq) {
    int c2 = (threadIdx.x & 63) * 2;
    int rg = threadIdx.x >> 6;          // 0..3
    int r0 = blockIdx.x * 250;
    v2f s = {0.f, 0.f}, q = {0.f, 0.f};
    for (int r = r0 + rg; r < r0 + 250; r += 4) {
        v2f v = *(const v2f*)&hpre[(size_t)r * HDV + c2];
        s += v;
        q = __builtin_elementwise_fma(v, v, q);
    }
    __shared__ v2f ls[256], lq[256];
    ls[threadIdx.x] = s; lq[threadIdx.x] = q;
    __syncthreads();
    if (rg == 0) {
        int b = threadIdx.x;
        s = ls[b] + ls[b + 64] + ls[b + 128] + ls[b + 192];
        q = lq[b] + lq[b + 64] + lq[b + 128] + lq[b + 192];
        atomicAdd(&bnsum[c2],     (double)s.x);
        atomicAdd(&bnsum[c2 + 1], (double)s.y);
        atomicAdd(&bnsumsq[c2],     (double)q.x);
        atomicAdd(&bnsumsq[c2 + 1], (double)q.y);
    }
}

// ---------------- pooling + MLP ----------------

// grid (NG, PSPLIT): partial sums with layer-3 BN+leaky fused; atomic add into zeroed pooled_sum
__global__ __launch_bounds__(256) void k_pool2(const float* __restrict__ hpre, const int* __restrict__ gstart,
                                               const double* __restrict__ bnsum, const double* __restrict__ bnsumsq,
                                               const float* __restrict__ g, const float* __restrict__ bb,
                                               float* __restrict__ pooled_sum) {
    __shared__ float ssc[HDV], ssh[HDV];
    int t = threadIdx.x;
    if (t < HDV) {
        int cc = chan_of_pos(t);
        double mu = bnsum[t] * (1.0 / NN);
        double var = bnsumsq[t] * (1.0 / NN) - mu * mu;
        double inv = rsqrt(var + 1e-5);
        float sc = (float)(inv * (double)g[cc]);
        ssc[t] = sc;
        ssh[t] = bb[cc] - (float)mu * sc;
    }
    __syncthreads();
    int gr = blockIdx.x, slice = blockIdx.y;
    int s = gstart[gr], e = gstart[gr + 1];
    int c = t & 127, half = t >> 7;
    float sc = ssc[c], sh = ssh[c];
    float acc = 0.f;
    for (int r = s + slice * 2 + half; r < e; r += PSPLIT * 2) {
        float v = fmaf(hpre[(size_t)r * HDV + c], sc, sh);
        acc += fmaxf(v, 0.01f * v);
    }
    __shared__ float ls[256];
    ls[t] = acc;
    __syncthreads();
    if (half == 0) atomicAdd(&pooled_sum[gr * HDV + c], acc + ls[t + 128]);
}

__global__ __launch_bounds__(512) void k_mlp(const float* __restrict__ pooled_sum, const int* __restrict__ gstart,
                                             const float* __restrict__ fc1w, const float* __restrict__ fc1b,
                                             const float* __restrict__ fc2w, const float* __restrict__ fc2b,
                                             float* __restrict__ out) {
    __shared__ float pl[NG * HDV];   // 32 KB (positional)
    __shared__ float hh[NG * 64];    // 16 KB
    int t = threadIdx.x;
    for (int i = t; i < NG * HDV; i += 512) {
        int gr = i >> 7;
        float cnt = (float)max(gstart[gr + 1] - gstart[gr], 1);
        pl[i] = pooled_sum[i] / cnt;
    }
    __syncthreads();
    for (int i = t; i < NG * 64; i += 512) {
        int gr = i >> 6, c = i & 63;
        float s = fc1b[c];
        for (int p = 0; p < HDV; ++p)
            s += pl[gr * HDV + p] * fc1w[chan_of_pos(p) * 64 + c];
        hh[i] = s > 0.f ? s : 0.f;
    }
    __syncthreads();
    if (t < NG) {
        float s = fc2b[0];
        for (int k = 0; k < 64; ++k) s += hh[t * 64 + k] * fc2w[k];
        out[t] = s;
    }
}

// ---------------- launch ----------------

extern "C" void kernel_launch(void* const* d_in, const int* in_sizes, int n_in,
                              void* d_out, int out_size, void* d_ws, size_t ws_size,
                              hipStream_t stream) {
    const float* x = (const float*)d_in[0];
    const int* ei = (const int*)d_in[1];
    const int* src = ei;
    const int* dst = ei + NE;
    const float* ea = (const float*)d_in[2];
    const int* batch = (const int*)d_in[3];
    const float* fc1w = (const float*)d_in[25];
    const float* fc1b = (const float*)d_in[26];
    const float* fc2w = (const float*)d_in[27];
    const float* fc2b = (const float*)d_in[28];
    float* out = (float*)d_out;

    char* ws = (char*)d_ws;
    size_t off = 0;
    auto alloc = [&](size_t bytes) -> void* {
        void* p = ws + off;
        off = (off + bytes + 255) & ~(size_t)255;
        return p;
    };

    // zero region (memset every launch)
    int* cnt = (int*)alloc(NN * 4);
    double* bnsum = (double*)alloc(3 * HDV * 8);
    double* bnsumsq = (double*)alloc(3 * HDV * 8);
    float* pooled_sum = (float*)alloc(NG * HDV * 4);
    size_t zero_bytes = off;

    int* rowptr = (int*)alloc((NN + 1) * 4);
    int* cursor = (int*)alloc(NN * 4);
    int* gstart = (int*)alloc((NG + 1) * 4);
    int* bsum = (int*)alloc(NSB * 4);
    int* boff = (int*)alloc(256 * 4);
    float* wlp = (float*)alloc(3 * HDV * HDV * 4);
    float* wrp = (float*)alloc(3 * HDV * HDV * 4);
    int* csr_src = (int*)alloc(((size_t)EF + 16) * 4);
    float* csr_ea = (float*)alloc(((size_t)EF * DEV + 64) * 4);
    __half* XLh = (__half*)alloc((size_t)NN * HDV * 2);
    float* XRb = (float*)alloc((size_t)NN * HDV * 4);
    float* hpre = (float*)alloc((size_t)NN * HDV * 4);
    (void)ws_size; (void)in_sizes; (void)n_in; (void)out_size;

    hipMemsetAsync(d_ws, 0, zero_bytes, stream);

    k_count<<<(NE + 255) / 256, 256, 0, stream>>>(dst, cnt);
    k_scan_a<<<NSB, 256, 0, stream>>>(cnt, bsum);
    k_scan_b<<<1, 256, 0, stream>>>(bsum, boff);
    k_scan_c<<<NSB, 256, 0, stream>>>(cnt, boff, rowptr, cursor);
    k_fill<<<(NE + 255) / 256, 256, 0, stream>>>(src, dst, ea, cursor, csr_src, csr_ea);
    k_wperm_all<<<(3 * HDV * HDV + 255) / 256 + 1, 256, 0, stream>>>(
        (const float*)d_in[4], (const float*)d_in[5],
        (const float*)d_in[11], (const float*)d_in[12],
        (const float*)d_in[18], (const float*)d_in[19], wlp, wrp, batch, gstart);

    const float* actp = x;
    int K = DINV;
    for (int L = 0; L < 3; ++L) {
        const float* we = (const float*)d_in[4 + 7 * L + 2];
        const float* a  = (const float*)d_in[4 + 7 * L + 3];
        const float* cb = (const float*)d_in[4 + 7 * L + 4];

        const double* bs  = (L == 0) ? nullptr : bnsum + (size_t)(L - 1) * HDV;
        const double* bsq = (L == 0) ? nullptr : bnsumsq + (size_t)(L - 1) * HDV;
        const float* gg   = (L == 0) ? nullptr : (const float*)d_in[4 + 7 * (L - 1) + 5];
        const float* bbp  = (L == 0) ? nullptr : (const float*)d_in[4 + 7 * (L - 1) + 6];

        k_gemm<<<dim3((NN + 127) / 128, 2), 256, 0, stream>>>(
            actp, K, wlp + (size_t)L * HDV * HDV, wrp + (size_t)L * HDV * HDV,
            XLh, XRb, bs, bsq, gg, bbp);
        k_gat<<<NN / 4, 256, 0, stream>>>(XLh, XRb, rowptr, csr_src, csr_ea, we, a, cb, hpre);
        k_bn_stats<<<160, 256, 0, stream>>>(hpre, bnsum + (size_t)L * HDV, bnsumsq + (size_t)L * HDV);
        actp = hpre;
        K = HDV;
    }

    k_pool2<<<dim3(NG, PSPLIT), 256, 0, stream>>>(
        hpre, gstart, bnsum + 2 * HDV, bnsumsq + 2 * HDV,
        (const float*)d_in[4 + 7 * 2 + 5], (const float*)d_in[4 + 7 * 2 + 6], pooled_sum);
    k_mlp<<<1, 512, 0, stream>>>(pooled_sum, gstart, fc1w, fc1b, fc2w, fc2b, out);
}